// Round 1
// baseline (633.048 us; speedup 1.0000x reference)
//
#include <hip/hip_runtime.h>
#include <math.h>

#define NN 50000
#define NE 800000
#define DD 128

// ---------------- degree + count ----------------
static __global__ void deg_kernel(const int* __restrict__ erow, const float* __restrict__ eval_,
                                  float* __restrict__ deg, int* __restrict__ counts, int n) {
    int e = blockIdx.x * blockDim.x + threadIdx.x;
    if (e < n) {
        int r = erow[e];
        atomicAdd(&deg[r], eval_[e]);
        atomicAdd(&counts[r], 1);
    }
}

static __global__ void clamp_deg_kernel(float* __restrict__ deg, int n) {
    int i = blockIdx.x * blockDim.x + threadIdx.x;
    if (i < n) {
        if (deg[i] == 0.0f) deg[i] = 1.0f;
    }
}

// x0 = R * deg^(-0.5)
static __global__ void init_x_kernel(const float* __restrict__ R, const float* __restrict__ deg,
                                     float* __restrict__ x, int total) {
    int i = blockIdx.x * blockDim.x + threadIdx.x;
    if (i < total) {
        float d = deg[i >> 7];  // i / 128
        x[i] = R[i] * (1.0f / sqrtf(d));
    }
}

// ---------------- exclusive scan over counts (single block) ----------------
static __global__ void scan_kernel(const int* __restrict__ counts, int* __restrict__ row_start, int n) {
    __shared__ int smem[1024];
    __shared__ int running;
    if (threadIdx.x == 0) running = 0;
    __syncthreads();
    for (int base = 0; base < n; base += 1024) {
        int i = base + (int)threadIdx.x;
        int v = (i < n) ? counts[i] : 0;
        smem[threadIdx.x] = v;
        __syncthreads();
        for (int off = 1; off < 1024; off <<= 1) {
            int t = (threadIdx.x >= (unsigned)off) ? smem[threadIdx.x - off] : 0;
            __syncthreads();
            if (threadIdx.x >= (unsigned)off) smem[threadIdx.x] += t;
            __syncthreads();
        }
        int incl = smem[threadIdx.x];
        if (i < n) row_start[i] = running + incl - v;  // exclusive prefix
        __syncthreads();
        if (threadIdx.x == 0) running += smem[1023];
        __syncthreads();
    }
    if (threadIdx.x == 0) row_start[n] = running;
}

// ---------------- scatter edges into CSR ----------------
static __global__ void scatter_kernel(const int* __restrict__ erow, const int* __restrict__ ecol,
                                      const float* __restrict__ eval_, const int* __restrict__ row_start,
                                      int* __restrict__ cursor, int* __restrict__ csr_col,
                                      float* __restrict__ csr_val, int n) {
    int e = blockIdx.x * blockDim.x + threadIdx.x;
    if (e < n) {
        int r = erow[e];
        int pos = row_start[r] + atomicAdd(&cursor[r], 1);
        csr_col[pos] = ecol[e];
        csr_val[pos] = eval_[e];
    }
}

// ---------------- fused SpMM + inv_deg + row-normalize + weighted accumulate ----------------
// one wave (64 lanes) per row; lane owns float2 (2 columns)
static __global__ __launch_bounds__(64) void spmm_fused_kernel(
    const int* __restrict__ row_start, const int* __restrict__ csr_col,
    const float* __restrict__ csr_val, const float* __restrict__ x,
    const float* __restrict__ deg, float* __restrict__ x_next,
    float* __restrict__ acc, float weight, int overwrite) {
    int row = blockIdx.x;
    int lane = threadIdx.x;  // 0..63
    int s = row_start[row];
    int e = row_start[row + 1];
    const float2* __restrict__ x2 = (const float2*)x;

    float ax = 0.0f, ay = 0.0f;
    for (int base = s; base < e; base += 64) {
        int j = base + lane;
        int cl = 0;
        float vl = 0.0f;
        if (j < e) { cl = csr_col[j]; vl = csr_val[j]; }
        int cnt = e - base; if (cnt > 64) cnt = 64;
        for (int k = 0; k < cnt; ++k) {
            int c = __shfl(cl, k);
            float v = __shfl(vl, k);
            float2 xv = x2[c * 64 + lane];  // 512B coalesced gather
            ax += v * xv.x;
            ay += v * xv.y;
        }
    }
    float id = 1.0f / deg[row];
    ax *= id;
    ay *= id;

    float2* xn2 = (float2*)x_next;
    float2 o; o.x = ax; o.y = ay;
    xn2[row * 64 + lane] = o;

    float ss = ax * ax + ay * ay;
#pragma unroll
    for (int off = 32; off > 0; off >>= 1) ss += __shfl_down(ss, off);
    ss = __shfl(ss, 0);
    float nrm = fmaxf(sqrtf(ss), 1e-12f);
    float w = weight / nrm;

    float2* acc2 = (float2*)acc;
    int idx = row * 64 + lane;
    if (overwrite) {
        float2 p; p.x = ax * w; p.y = ay * w;
        acc2[idx] = p;
    } else {
        float2 p = acc2[idx];
        p.x += ax * w;
        p.y += ay * w;
        acc2[idx] = p;
    }
}

// ---------------- column statistics (double accumulation) ----------------
static __global__ void colstats_kernel(const float* __restrict__ acc,
                                       double* __restrict__ csum, double* __restrict__ csumsq, int n) {
    int col = threadIdx.x;  // 0..127
    double s = 0.0, q = 0.0;
    for (int r = blockIdx.x; r < n; r += gridDim.x) {
        float v = acc[r * DD + col];
        s += (double)v;
        q += (double)v * (double)v;
    }
    atomicAdd(&csum[col], s);
    atomicAdd(&csumsq[col], q);
}

static __global__ void stats_kernel(const double* __restrict__ csum, const double* __restrict__ csumsq,
                                    float* __restrict__ mean, float* __restrict__ invstd, int n) {
    int c = threadIdx.x;  // 128 threads
    double m = csum[c] / (double)n;
    double var = (csumsq[c] - (double)n * m * m) / (double)(n - 1);
    if (var < 0.0) var = 0.0;
    double sd = sqrt(var);
    if (sd == 0.0) sd = 1.0;
    mean[c] = (float)m;
    invstd[c] = (float)(1.0 / sd);
}

static __global__ void normalize_kernel(float* __restrict__ out, const float* __restrict__ mean,
                                        const float* __restrict__ invstd, int total) {
    int i = blockIdx.x * blockDim.x + threadIdx.x;
    if (i < total) {
        int c = i & 127;
        out[i] = (out[i] - mean[c]) * invstd[c];
    }
}

extern "C" void kernel_launch(void* const* d_in, const int* in_sizes, int n_in,
                              void* d_out, int out_size, void* d_ws, size_t ws_size,
                              hipStream_t stream) {
    const int* erow = (const int*)d_in[0];
    const int* ecol = (const int*)d_in[1];
    const float* eval_ = (const float*)d_in[2];
    const float* R = (const float*)d_in[3];
    float* out = (float*)d_out;  // acc lives here, normalized in place at the end

    // workspace layout
    char* ws = (char*)d_ws;
    size_t off = 0;
    auto alloc = [&](size_t bytes) -> char* {
        char* p = ws + off;
        off += (bytes + 255) & ~(size_t)255;
        return p;
    };
    float* deg      = (float*)alloc(NN * sizeof(float));
    int* counts     = (int*)alloc(NN * sizeof(int));
    int* row_start  = (int*)alloc((NN + 1) * sizeof(int));
    int* cursor     = (int*)alloc(NN * sizeof(int));
    int* csr_col    = (int*)alloc(NE * sizeof(int));
    float* csr_val  = (float*)alloc(NE * sizeof(float));
    float* x_a      = (float*)alloc((size_t)NN * DD * sizeof(float));
    float* x_b      = (float*)alloc((size_t)NN * DD * sizeof(float));
    double* csum    = (double*)alloc(DD * sizeof(double));
    double* csumsq  = (double*)alloc(DD * sizeof(double));
    float* meanbuf  = (float*)alloc(DD * sizeof(float));
    float* invstdb  = (float*)alloc(DD * sizeof(float));

    // zero what we accumulate into (ws is poisoned 0xAA before every call)
    hipMemsetAsync(deg, 0, NN * sizeof(float), stream);
    hipMemsetAsync(counts, 0, NN * sizeof(int), stream);
    hipMemsetAsync(cursor, 0, NN * sizeof(int), stream);
    hipMemsetAsync(csum, 0, DD * sizeof(double), stream);
    hipMemsetAsync(csumsq, 0, DD * sizeof(double), stream);

    const int total = NN * DD;

    deg_kernel<<<(NE + 255) / 256, 256, 0, stream>>>(erow, eval_, deg, counts, NE);
    clamp_deg_kernel<<<(NN + 255) / 256, 256, 0, stream>>>(deg, NN);
    init_x_kernel<<<(total + 255) / 256, 256, 0, stream>>>(R, deg, x_a, total);
    scan_kernel<<<1, 1024, 0, stream>>>(counts, row_start, NN);
    scatter_kernel<<<(NE + 255) / 256, 256, 0, stream>>>(erow, ecol, eval_, row_start, cursor,
                                                         csr_col, csr_val, NE);

    const float weights[4] = {1.0f, 1.0f, 7.81f, 45.28f};
    float* xs[2] = {x_a, x_b};
    for (int i = 0; i < 4; ++i) {
        spmm_fused_kernel<<<NN, 64, 0, stream>>>(row_start, csr_col, csr_val,
                                                 xs[i & 1], deg, xs[(i + 1) & 1],
                                                 out, weights[i], i == 0 ? 1 : 0);
    }

    colstats_kernel<<<512, DD, 0, stream>>>(out, csum, csumsq, NN);
    stats_kernel<<<1, DD, 0, stream>>>(csum, csumsq, meanbuf, invstdb, NN);
    normalize_kernel<<<(total + 255) / 256, 256, 0, stream>>>(out, meanbuf, invstdb, total);
}

// Round 2
// 555.273 us; speedup vs baseline: 1.1401x; 1.1401x over previous
//
#include <hip/hip_runtime.h>
#include <math.h>

#define NN 50000
#define NE 800000
#define DD 128
#define SCAN_BS 256
#define SCAN_NBLK ((NN + SCAN_BS - 1) / SCAN_BS)   // 196 <= 256

// ---------------- degree + count ----------------
static __global__ void deg_kernel(const int* __restrict__ erow, const float* __restrict__ eval_,
                                  float* __restrict__ deg, int* __restrict__ counts, int n) {
    int e = blockIdx.x * blockDim.x + threadIdx.x;
    if (e < n) {
        int r = erow[e];
        atomicAdd(&deg[r], eval_[e]);
        atomicAdd(&counts[r], 1);
    }
}

static __global__ void clamp_deg_kernel(float* __restrict__ deg, int n) {
    int i = blockIdx.x * blockDim.x + threadIdx.x;
    if (i < n) {
        if (deg[i] == 0.0f) deg[i] = 1.0f;
    }
}

// x0 = R * deg^(-0.5)
static __global__ void init_x_kernel(const float* __restrict__ R, const float* __restrict__ deg,
                                     float* __restrict__ x, int total) {
    int i = blockIdx.x * blockDim.x + threadIdx.x;
    if (i < total) {
        float d = deg[i >> 7];  // i / 128
        x[i] = R[i] * (1.0f / sqrtf(d));
    }
}

// ---------------- three-phase exclusive scan over counts ----------------
static __global__ void scan_phase1(const int* __restrict__ counts, int* __restrict__ partials, int n) {
    __shared__ int smem[SCAN_BS];
    int i = blockIdx.x * SCAN_BS + threadIdx.x;
    smem[threadIdx.x] = (i < n) ? counts[i] : 0;
    __syncthreads();
    for (int off = SCAN_BS / 2; off > 0; off >>= 1) {
        if (threadIdx.x < (unsigned)off) smem[threadIdx.x] += smem[threadIdx.x + off];
        __syncthreads();
    }
    if (threadIdx.x == 0) partials[blockIdx.x] = smem[0];
}

static __global__ void scan_phase2(int* __restrict__ partials, int* __restrict__ row_start, int nblk) {
    __shared__ int smem[SCAN_BS];
    int v = (threadIdx.x < (unsigned)nblk) ? partials[threadIdx.x] : 0;
    smem[threadIdx.x] = v;
    __syncthreads();
    for (int off = 1; off < SCAN_BS; off <<= 1) {
        int t = (threadIdx.x >= (unsigned)off) ? smem[threadIdx.x - off] : 0;
        __syncthreads();
        smem[threadIdx.x] += t;
        __syncthreads();
    }
    if (threadIdx.x < (unsigned)nblk) partials[threadIdx.x] = smem[threadIdx.x] - v;  // exclusive
    if (threadIdx.x == (unsigned)(nblk - 1)) row_start[NN] = smem[threadIdx.x];       // total
}

static __global__ void scan_phase3(const int* __restrict__ counts, const int* __restrict__ partials,
                                   int* __restrict__ row_start, int n) {
    __shared__ int smem[SCAN_BS];
    int i = blockIdx.x * SCAN_BS + threadIdx.x;
    int v = (i < n) ? counts[i] : 0;
    smem[threadIdx.x] = v;
    __syncthreads();
    for (int off = 1; off < SCAN_BS; off <<= 1) {
        int t = (threadIdx.x >= (unsigned)off) ? smem[threadIdx.x - off] : 0;
        __syncthreads();
        smem[threadIdx.x] += t;
        __syncthreads();
    }
    if (i < n) row_start[i] = partials[blockIdx.x] + smem[threadIdx.x] - v;
}

// ---------------- scatter edges into CSR ----------------
static __global__ void scatter_kernel(const int* __restrict__ erow, const int* __restrict__ ecol,
                                      const float* __restrict__ eval_, const int* __restrict__ row_start,
                                      int* __restrict__ cursor, int* __restrict__ csr_col,
                                      float* __restrict__ csr_val, int n) {
    int e = blockIdx.x * blockDim.x + threadIdx.x;
    if (e < n) {
        int r = erow[e];
        int pos = row_start[r] + atomicAdd(&cursor[r], 1);
        csr_col[pos] = ecol[e];
        csr_val[pos] = eval_[e];
    }
}

// ---------------- fused SpMM + inv_deg + row-normalize + weighted accumulate ----------------
// one wave (64 lanes) per row; lane owns float2 (2 columns)
static __global__ __launch_bounds__(64) void spmm_fused_kernel(
    const int* __restrict__ row_start, const int* __restrict__ csr_col,
    const float* __restrict__ csr_val, const float* __restrict__ x,
    const float* __restrict__ deg, float* __restrict__ x_next,
    float* __restrict__ acc, float weight, int overwrite) {
    int row = blockIdx.x;
    int lane = threadIdx.x;  // 0..63
    int s = row_start[row];
    int e = row_start[row + 1];
    const float2* __restrict__ x2 = (const float2*)x;

    float ax = 0.0f, ay = 0.0f;
    for (int base = s; base < e; base += 64) {
        int j = base + lane;
        int cl = 0;
        float vl = 0.0f;
        if (j < e) { cl = csr_col[j]; vl = csr_val[j]; }
        int cnt = e - base; if (cnt > 64) cnt = 64;
        for (int k = 0; k < cnt; ++k) {
            int c = __shfl(cl, k);
            float v = __shfl(vl, k);
            float2 xv = x2[c * 64 + lane];  // 512B coalesced gather
            ax += v * xv.x;
            ay += v * xv.y;
        }
    }
    float id = 1.0f / deg[row];
    ax *= id;
    ay *= id;

    float2* xn2 = (float2*)x_next;
    float2 o; o.x = ax; o.y = ay;
    xn2[row * 64 + lane] = o;

    float ss = ax * ax + ay * ay;
#pragma unroll
    for (int off = 32; off > 0; off >>= 1) ss += __shfl_down(ss, off);
    ss = __shfl(ss, 0);
    float nrm = fmaxf(sqrtf(ss), 1e-12f);
    float w = weight / nrm;

    float2* acc2 = (float2*)acc;
    int idx = row * 64 + lane;
    if (overwrite) {
        float2 p; p.x = ax * w; p.y = ay * w;
        acc2[idx] = p;
    } else {
        float2 p = acc2[idx];
        p.x += ax * w;
        p.y += ay * w;
        acc2[idx] = p;
    }
}

// ---------------- column statistics (double accumulation) ----------------
static __global__ void colstats_kernel(const float* __restrict__ acc,
                                       double* __restrict__ csum, double* __restrict__ csumsq, int n) {
    int col = threadIdx.x;  // 0..127
    double s = 0.0, q = 0.0;
    for (int r = blockIdx.x; r < n; r += gridDim.x) {
        float v = acc[r * DD + col];
        s += (double)v;
        q += (double)v * (double)v;
    }
    atomicAdd(&csum[col], s);
    atomicAdd(&csumsq[col], q);
}

static __global__ void stats_kernel(const double* __restrict__ csum, const double* __restrict__ csumsq,
                                    float* __restrict__ mean, float* __restrict__ invstd, int n) {
    int c = threadIdx.x;  // 128 threads
    double m = csum[c] / (double)n;
    double var = (csumsq[c] - (double)n * m * m) / (double)(n - 1);
    if (var < 0.0) var = 0.0;
    double sd = sqrt(var);
    if (sd == 0.0) sd = 1.0;
    mean[c] = (float)m;
    invstd[c] = (float)(1.0 / sd);
}

static __global__ void normalize_kernel(float* __restrict__ out, const float* __restrict__ mean,
                                        const float* __restrict__ invstd, int total) {
    int i = blockIdx.x * blockDim.x + threadIdx.x;
    if (i < total) {
        int c = i & 127;
        out[i] = (out[i] - mean[c]) * invstd[c];
    }
}

extern "C" void kernel_launch(void* const* d_in, const int* in_sizes, int n_in,
                              void* d_out, int out_size, void* d_ws, size_t ws_size,
                              hipStream_t stream) {
    const int* erow = (const int*)d_in[0];
    const int* ecol = (const int*)d_in[1];
    const float* eval_ = (const float*)d_in[2];
    const float* R = (const float*)d_in[3];
    float* out = (float*)d_out;  // acc lives here, normalized in place at the end

    // workspace layout
    char* ws = (char*)d_ws;
    size_t off = 0;
    auto alloc = [&](size_t bytes) -> char* {
        char* p = ws + off;
        off += (bytes + 255) & ~(size_t)255;
        return p;
    };
    float* deg      = (float*)alloc(NN * sizeof(float));
    int* counts     = (int*)alloc(NN * sizeof(int));
    int* row_start  = (int*)alloc((NN + 1) * sizeof(int));
    int* cursor     = (int*)alloc(NN * sizeof(int));
    int* partials   = (int*)alloc(SCAN_NBLK * sizeof(int));
    int* csr_col    = (int*)alloc(NE * sizeof(int));
    float* csr_val  = (float*)alloc(NE * sizeof(float));
    float* x_a      = (float*)alloc((size_t)NN * DD * sizeof(float));
    float* x_b      = (float*)alloc((size_t)NN * DD * sizeof(float));
    double* csum    = (double*)alloc(DD * sizeof(double));
    double* csumsq  = (double*)alloc(DD * sizeof(double));
    float* meanbuf  = (float*)alloc(DD * sizeof(float));
    float* invstdb  = (float*)alloc(DD * sizeof(float));

    // zero what we accumulate into (ws is poisoned 0xAA before every call)
    hipMemsetAsync(deg, 0, NN * sizeof(float), stream);
    hipMemsetAsync(counts, 0, NN * sizeof(int), stream);
    hipMemsetAsync(cursor, 0, NN * sizeof(int), stream);
    hipMemsetAsync(csum, 0, DD * sizeof(double), stream);
    hipMemsetAsync(csumsq, 0, DD * sizeof(double), stream);

    const int total = NN * DD;

    deg_kernel<<<(NE + 255) / 256, 256, 0, stream>>>(erow, eval_, deg, counts, NE);
    clamp_deg_kernel<<<(NN + 255) / 256, 256, 0, stream>>>(deg, NN);
    init_x_kernel<<<(total + 255) / 256, 256, 0, stream>>>(R, deg, x_a, total);

    scan_phase1<<<SCAN_NBLK, SCAN_BS, 0, stream>>>(counts, partials, NN);
    scan_phase2<<<1, SCAN_BS, 0, stream>>>(partials, row_start, SCAN_NBLK);
    scan_phase3<<<SCAN_NBLK, SCAN_BS, 0, stream>>>(counts, partials, row_start, NN);

    scatter_kernel<<<(NE + 255) / 256, 256, 0, stream>>>(erow, ecol, eval_, row_start, cursor,
                                                         csr_col, csr_val, NE);

    const float weights[4] = {1.0f, 1.0f, 7.81f, 45.28f};
    float* xs[2] = {x_a, x_b};
    for (int i = 0; i < 4; ++i) {
        spmm_fused_kernel<<<NN, 64, 0, stream>>>(row_start, csr_col, csr_val,
                                                 xs[i & 1], deg, xs[(i + 1) & 1],
                                                 out, weights[i], i == 0 ? 1 : 0);
    }

    colstats_kernel<<<512, DD, 0, stream>>>(out, csum, csumsq, NN);
    stats_kernel<<<1, DD, 0, stream>>>(csum, csumsq, meanbuf, invstdb, NN);
    normalize_kernel<<<(total + 255) / 256, 256, 0, stream>>>(out, meanbuf, invstdb, total);
}

// Round 3
// 517.100 us; speedup vs baseline: 1.2242x; 1.0738x over previous
//
#include <hip/hip_runtime.h>
#include <math.h>

#define NN 50000
#define NE 800000
#define DD 128
#define NREP 8
#define SCAN_BS 256
#define SCAN_NBLK ((NN + SCAN_BS - 1) / SCAN_BS)   // 196 <= 256

// ---------------- edge histogram into 8 replicated count arrays ----------------
static __global__ void count_kernel(const int* __restrict__ erow, int* __restrict__ counts_rep, int n) {
    int e = blockIdx.x * blockDim.x + threadIdx.x;
    if (e < n) {
        int k = blockIdx.x & (NREP - 1);
        atomicAdd(&counts_rep[k * NN + erow[e]], 1);
    }
}

// fold replicas -> counts; per-replica exclusive offsets -> rep_base
static __global__ void rep_prefix_kernel(const int* __restrict__ counts_rep, int* __restrict__ rep_base,
                                         int* __restrict__ counts, int n) {
    int r = blockIdx.x * blockDim.x + threadIdx.x;
    if (r < n) {
        int run = 0;
#pragma unroll
        for (int k = 0; k < NREP; ++k) {
            int c = counts_rep[k * NN + r];
            rep_base[k * NN + r] = run;
            run += c;
        }
        counts[r] = run;
    }
}

// ---------------- three-phase exclusive scan over counts ----------------
static __global__ void scan_phase1(const int* __restrict__ counts, int* __restrict__ partials, int n) {
    __shared__ int smem[SCAN_BS];
    int i = blockIdx.x * SCAN_BS + threadIdx.x;
    smem[threadIdx.x] = (i < n) ? counts[i] : 0;
    __syncthreads();
    for (int off = SCAN_BS / 2; off > 0; off >>= 1) {
        if (threadIdx.x < (unsigned)off) smem[threadIdx.x] += smem[threadIdx.x + off];
        __syncthreads();
    }
    if (threadIdx.x == 0) partials[blockIdx.x] = smem[0];
}

static __global__ void scan_phase2(int* __restrict__ partials, int* __restrict__ row_start, int nblk) {
    __shared__ int smem[SCAN_BS];
    int v = (threadIdx.x < (unsigned)nblk) ? partials[threadIdx.x] : 0;
    smem[threadIdx.x] = v;
    __syncthreads();
    for (int off = 1; off < SCAN_BS; off <<= 1) {
        int t = (threadIdx.x >= (unsigned)off) ? smem[threadIdx.x - off] : 0;
        __syncthreads();
        smem[threadIdx.x] += t;
        __syncthreads();
    }
    if (threadIdx.x < (unsigned)nblk) partials[threadIdx.x] = smem[threadIdx.x] - v;  // exclusive
    if (threadIdx.x == (unsigned)(nblk - 1)) row_start[NN] = smem[threadIdx.x];       // total
}

static __global__ void scan_phase3(const int* __restrict__ counts, const int* __restrict__ partials,
                                   int* __restrict__ row_start, int n) {
    __shared__ int smem[SCAN_BS];
    int i = blockIdx.x * SCAN_BS + threadIdx.x;
    int v = (i < n) ? counts[i] : 0;
    smem[threadIdx.x] = v;
    __syncthreads();
    for (int off = 1; off < SCAN_BS; off <<= 1) {
        int t = (threadIdx.x >= (unsigned)off) ? smem[threadIdx.x - off] : 0;
        __syncthreads();
        smem[threadIdx.x] += t;
        __syncthreads();
    }
    if (i < n) row_start[i] = partials[blockIdx.x] + smem[threadIdx.x] - v;
}

// ---------------- scatter edges into CSR (8-way replicated cursors) ----------------
static __global__ void scatter_kernel(const int* __restrict__ erow, const int* __restrict__ ecol,
                                      const float* __restrict__ eval_, const int* __restrict__ row_start,
                                      const int* __restrict__ rep_base, int* __restrict__ cursor_rep,
                                      int* __restrict__ csr_col, float* __restrict__ csr_val, int n) {
    int e = blockIdx.x * blockDim.x + threadIdx.x;
    if (e < n) {
        int k = blockIdx.x & (NREP - 1);
        int r = erow[e];
        int pos = row_start[r] + rep_base[k * NN + r] + atomicAdd(&cursor_rep[k * NN + r], 1);
        csr_col[pos] = ecol[e];
        csr_val[pos] = eval_[e];
    }
}

// ---------------- degree from CSR row sums (no atomics), clamp zeros ----------------
static __global__ void deg_from_csr_kernel(const int* __restrict__ row_start,
                                           const float* __restrict__ csr_val,
                                           float* __restrict__ deg, int n) {
    int r = blockIdx.x * blockDim.x + threadIdx.x;
    if (r < n) {
        int s = row_start[r], e = row_start[r + 1];
        float sum = 0.0f;
        for (int j = s; j < e; ++j) sum += csr_val[j];
        deg[r] = (sum == 0.0f) ? 1.0f : sum;
    }
}

// x0 = R * deg^(-0.5)
static __global__ void init_x_kernel(const float* __restrict__ R, const float* __restrict__ deg,
                                     float* __restrict__ x, int total) {
    int i = blockIdx.x * blockDim.x + threadIdx.x;
    if (i < total) {
        float d = deg[i >> 7];  // i / 128
        x[i] = R[i] * (1.0f / sqrtf(d));
    }
}

// ---------------- fused SpMM + inv_deg + row-normalize + weighted accumulate ----------------
// one wave (64 lanes) per row; lane owns float2 (2 columns)
static __global__ __launch_bounds__(64) void spmm_fused_kernel(
    const int* __restrict__ row_start, const int* __restrict__ csr_col,
    const float* __restrict__ csr_val, const float* __restrict__ x,
    const float* __restrict__ deg, float* __restrict__ x_next,
    float* __restrict__ acc, float weight, int overwrite) {
    int row = blockIdx.x;
    int lane = threadIdx.x;  // 0..63
    int s = row_start[row];
    int e = row_start[row + 1];
    const float2* __restrict__ x2 = (const float2*)x;

    float ax = 0.0f, ay = 0.0f;
    for (int base = s; base < e; base += 64) {
        int j = base + lane;
        int cl = 0;
        float vl = 0.0f;
        if (j < e) { cl = csr_col[j]; vl = csr_val[j]; }
        int cnt = e - base; if (cnt > 64) cnt = 64;
        for (int k = 0; k < cnt; ++k) {
            int c = __shfl(cl, k);
            float v = __shfl(vl, k);
            float2 xv = x2[c * 64 + lane];  // 512B coalesced gather
            ax += v * xv.x;
            ay += v * xv.y;
        }
    }
    float id = 1.0f / deg[row];
    ax *= id;
    ay *= id;

    float2* xn2 = (float2*)x_next;
    float2 o; o.x = ax; o.y = ay;
    xn2[row * 64 + lane] = o;

    float ss = ax * ax + ay * ay;
#pragma unroll
    for (int off = 32; off > 0; off >>= 1) ss += __shfl_down(ss, off);
    ss = __shfl(ss, 0);
    float nrm = fmaxf(sqrtf(ss), 1e-12f);
    float w = weight / nrm;

    float2* acc2 = (float2*)acc;
    int idx = row * 64 + lane;
    if (overwrite) {
        float2 p; p.x = ax * w; p.y = ay * w;
        acc2[idx] = p;
    } else {
        float2 p = acc2[idx];
        p.x += ax * w;
        p.y += ay * w;
        acc2[idx] = p;
    }
}

// ---------------- column statistics (double accumulation) ----------------
static __global__ void colstats_kernel(const float* __restrict__ acc,
                                       double* __restrict__ csum, double* __restrict__ csumsq, int n) {
    int col = threadIdx.x;  // 0..127
    double s = 0.0, q = 0.0;
    for (int r = blockIdx.x; r < n; r += gridDim.x) {
        float v = acc[r * DD + col];
        s += (double)v;
        q += (double)v * (double)v;
    }
    atomicAdd(&csum[col], s);
    atomicAdd(&csumsq[col], q);
}

static __global__ void stats_kernel(const double* __restrict__ csum, const double* __restrict__ csumsq,
                                    float* __restrict__ mean, float* __restrict__ invstd, int n) {
    int c = threadIdx.x;  // 128 threads
    double m = csum[c] / (double)n;
    double var = (csumsq[c] - (double)n * m * m) / (double)(n - 1);
    if (var < 0.0) var = 0.0;
    double sd = sqrt(var);
    if (sd == 0.0) sd = 1.0;
    mean[c] = (float)m;
    invstd[c] = (float)(1.0 / sd);
}

static __global__ void normalize_kernel(float* __restrict__ out, const float* __restrict__ mean,
                                        const float* __restrict__ invstd, int total) {
    int i = blockIdx.x * blockDim.x + threadIdx.x;
    if (i < total) {
        int c = i & 127;
        out[i] = (out[i] - mean[c]) * invstd[c];
    }
}

extern "C" void kernel_launch(void* const* d_in, const int* in_sizes, int n_in,
                              void* d_out, int out_size, void* d_ws, size_t ws_size,
                              hipStream_t stream) {
    const int* erow = (const int*)d_in[0];
    const int* ecol = (const int*)d_in[1];
    const float* eval_ = (const float*)d_in[2];
    const float* R = (const float*)d_in[3];
    float* out = (float*)d_out;  // acc lives here, normalized in place at the end

    // workspace layout
    char* ws = (char*)d_ws;
    size_t off = 0;
    auto alloc = [&](size_t bytes) -> char* {
        char* p = ws + off;
        off += (bytes + 255) & ~(size_t)255;
        return p;
    };
    float* deg       = (float*)alloc(NN * sizeof(float));
    int* counts      = (int*)alloc(NN * sizeof(int));
    int* counts_rep  = (int*)alloc((size_t)NREP * NN * sizeof(int));
    int* rep_base    = (int*)alloc((size_t)NREP * NN * sizeof(int));
    int* cursor_rep  = (int*)alloc((size_t)NREP * NN * sizeof(int));
    int* row_start   = (int*)alloc((NN + 1) * sizeof(int));
    int* partials    = (int*)alloc(SCAN_NBLK * sizeof(int));
    int* csr_col     = (int*)alloc(NE * sizeof(int));
    float* csr_val   = (float*)alloc(NE * sizeof(float));
    float* x_a       = (float*)alloc((size_t)NN * DD * sizeof(float));
    float* x_b       = (float*)alloc((size_t)NN * DD * sizeof(float));
    double* csum     = (double*)alloc(DD * sizeof(double));
    double* csumsq   = (double*)alloc(DD * sizeof(double));
    float* meanbuf   = (float*)alloc(DD * sizeof(float));
    float* invstdb   = (float*)alloc(DD * sizeof(float));

    // zero what we accumulate into (ws is poisoned 0xAA before every call)
    hipMemsetAsync(counts_rep, 0, (size_t)NREP * NN * sizeof(int), stream);
    hipMemsetAsync(cursor_rep, 0, (size_t)NREP * NN * sizeof(int), stream);
    hipMemsetAsync(csum, 0, DD * sizeof(double), stream);
    hipMemsetAsync(csumsq, 0, DD * sizeof(double), stream);

    const int total = NN * DD;

    count_kernel<<<(NE + 255) / 256, 256, 0, stream>>>(erow, counts_rep, NE);
    rep_prefix_kernel<<<(NN + 255) / 256, 256, 0, stream>>>(counts_rep, rep_base, counts, NN);

    scan_phase1<<<SCAN_NBLK, SCAN_BS, 0, stream>>>(counts, partials, NN);
    scan_phase2<<<1, SCAN_BS, 0, stream>>>(partials, row_start, SCAN_NBLK);
    scan_phase3<<<SCAN_NBLK, SCAN_BS, 0, stream>>>(counts, partials, row_start, NN);

    scatter_kernel<<<(NE + 255) / 256, 256, 0, stream>>>(erow, ecol, eval_, row_start, rep_base,
                                                         cursor_rep, csr_col, csr_val, NE);

    deg_from_csr_kernel<<<(NN + 255) / 256, 256, 0, stream>>>(row_start, csr_val, deg, NN);
    init_x_kernel<<<(total + 255) / 256, 256, 0, stream>>>(R, deg, x_a, total);

    const float weights[4] = {1.0f, 1.0f, 7.81f, 45.28f};
    float* xs[2] = {x_a, x_b};
    for (int i = 0; i < 4; ++i) {
        spmm_fused_kernel<<<NN, 64, 0, stream>>>(row_start, csr_col, csr_val,
                                                 xs[i & 1], deg, xs[(i + 1) & 1],
                                                 out, weights[i], i == 0 ? 1 : 0);
    }

    colstats_kernel<<<512, DD, 0, stream>>>(out, csum, csumsq, NN);
    stats_kernel<<<1, DD, 0, stream>>>(csum, csumsq, meanbuf, invstdb, NN);
    normalize_kernel<<<(total + 255) / 256, 256, 0, stream>>>(out, meanbuf, invstdb, total);
}

// Round 4
// 401.939 us; speedup vs baseline: 1.5750x; 1.2865x over previous
//
#include <hip/hip_runtime.h>
#include <math.h>

#define NN 50000
#define NE 800000
#define DD 128
#define NREP 8
#define SCAN_BS 256
#define SCAN_NBLK ((NN + SCAN_BS - 1) / SCAN_BS)   // 196 <= 256

// ---------------- bf16 helpers (x stored as bf16 pairs packed in uint) ----------------
static __device__ __forceinline__ float blo(unsigned int p) {  // low ushort -> float
    return __uint_as_float(p << 16);
}
static __device__ __forceinline__ float bhi(unsigned int p) {  // high ushort -> float
    return __uint_as_float(p & 0xffff0000u);
}
static __device__ __forceinline__ unsigned int pack2bf(float a, float b) {
    // a -> low half (even col), b -> high half (odd col), round-to-nearest-even
    unsigned int ua = __float_as_uint(a);
    unsigned int ub = __float_as_uint(b);
    ua = ua + 0x7FFFu + ((ua >> 16) & 1u);
    ub = ub + 0x7FFFu + ((ub >> 16) & 1u);
    return (ua >> 16) | (ub & 0xffff0000u);
}

// ---------------- edge histogram into 8 replicated count arrays ----------------
static __global__ void count_kernel(const int* __restrict__ erow, int* __restrict__ counts_rep, int n) {
    int e = blockIdx.x * blockDim.x + threadIdx.x;
    if (e < n) {
        int k = blockIdx.x & (NREP - 1);
        atomicAdd(&counts_rep[k * NN + erow[e]], 1);
    }
}

// fold replicas -> counts; per-replica exclusive offsets -> rep_base
static __global__ void rep_prefix_kernel(const int* __restrict__ counts_rep, int* __restrict__ rep_base,
                                         int* __restrict__ counts, int n) {
    int r = blockIdx.x * blockDim.x + threadIdx.x;
    if (r < n) {
        int run = 0;
#pragma unroll
        for (int k = 0; k < NREP; ++k) {
            int c = counts_rep[k * NN + r];
            rep_base[k * NN + r] = run;
            run += c;
        }
        counts[r] = run;
    }
}

// ---------------- three-phase exclusive scan over counts ----------------
static __global__ void scan_phase1(const int* __restrict__ counts, int* __restrict__ partials, int n) {
    __shared__ int smem[SCAN_BS];
    int i = blockIdx.x * SCAN_BS + threadIdx.x;
    smem[threadIdx.x] = (i < n) ? counts[i] : 0;
    __syncthreads();
    for (int off = SCAN_BS / 2; off > 0; off >>= 1) {
        if (threadIdx.x < (unsigned)off) smem[threadIdx.x] += smem[threadIdx.x + off];
        __syncthreads();
    }
    if (threadIdx.x == 0) partials[blockIdx.x] = smem[0];
}

static __global__ void scan_phase2(int* __restrict__ partials, int* __restrict__ row_start, int nblk) {
    __shared__ int smem[SCAN_BS];
    int v = (threadIdx.x < (unsigned)nblk) ? partials[threadIdx.x] : 0;
    smem[threadIdx.x] = v;
    __syncthreads();
    for (int off = 1; off < SCAN_BS; off <<= 1) {
        int t = (threadIdx.x >= (unsigned)off) ? smem[threadIdx.x - off] : 0;
        __syncthreads();
        smem[threadIdx.x] += t;
        __syncthreads();
    }
    if (threadIdx.x < (unsigned)nblk) partials[threadIdx.x] = smem[threadIdx.x] - v;  // exclusive
    if (threadIdx.x == (unsigned)(nblk - 1)) row_start[NN] = smem[threadIdx.x];       // total
}

static __global__ void scan_phase3(const int* __restrict__ counts, const int* __restrict__ partials,
                                   int* __restrict__ row_start, int n) {
    __shared__ int smem[SCAN_BS];
    int i = blockIdx.x * SCAN_BS + threadIdx.x;
    int v = (i < n) ? counts[i] : 0;
    smem[threadIdx.x] = v;
    __syncthreads();
    for (int off = 1; off < SCAN_BS; off <<= 1) {
        int t = (threadIdx.x >= (unsigned)off) ? smem[threadIdx.x - off] : 0;
        __syncthreads();
        smem[threadIdx.x] += t;
        __syncthreads();
    }
    if (i < n) row_start[i] = partials[blockIdx.x] + smem[threadIdx.x] - v;
}

// ---------------- scatter edges into CSR (8-way replicated cursors) ----------------
static __global__ void scatter_kernel(const int* __restrict__ erow, const int* __restrict__ ecol,
                                      const float* __restrict__ eval_, const int* __restrict__ row_start,
                                      const int* __restrict__ rep_base, int* __restrict__ cursor_rep,
                                      int* __restrict__ csr_col, float* __restrict__ csr_val, int n) {
    int e = blockIdx.x * blockDim.x + threadIdx.x;
    if (e < n) {
        int k = blockIdx.x & (NREP - 1);
        int r = erow[e];
        int pos = row_start[r] + rep_base[k * NN + r] + atomicAdd(&cursor_rep[k * NN + r], 1);
        csr_col[pos] = ecol[e];
        csr_val[pos] = eval_[e];
    }
}

// ---------------- degree from CSR row sums (no atomics), clamp zeros ----------------
static __global__ void deg_from_csr_kernel(const int* __restrict__ row_start,
                                           const float* __restrict__ csr_val,
                                           float* __restrict__ deg, int n) {
    int r = blockIdx.x * blockDim.x + threadIdx.x;
    if (r < n) {
        int s = row_start[r], e = row_start[r + 1];
        float sum = 0.0f;
        for (int j = s; j < e; ++j) sum += csr_val[j];
        deg[r] = (sum == 0.0f) ? 1.0f : sum;
    }
}

// x0 = R * deg^(-0.5), stored bf16-packed (one uint = 2 cols)
static __global__ void init_x_kernel(const float* __restrict__ R, const float* __restrict__ deg,
                                     unsigned int* __restrict__ xq, int npairs) {
    int i = blockIdx.x * blockDim.x + threadIdx.x;
    if (i < npairs) {
        float d = deg[i >> 6];  // 64 uints per row
        float sc = rsqrtf(d);
        float a = R[2 * i] * sc;
        float b = R[2 * i + 1] * sc;
        xq[i] = pack2bf(a, b);
    }
}

// ---------------- fused SpMM + inv_deg + row-normalize + weighted accumulate ----------------
// 256 threads = 4 waves per block; one wave per row; lane owns 2 columns (bf16 pair)
static __global__ __launch_bounds__(256) void spmm_fused_kernel(
    const int* __restrict__ row_start, const int* __restrict__ csr_col,
    const float* __restrict__ csr_val, const unsigned int* __restrict__ x,
    const float* __restrict__ deg, unsigned int* __restrict__ x_next,
    float* __restrict__ acc, float weight, int overwrite) {
    int wave = threadIdx.x >> 6;
    int lane = threadIdx.x & 63;
    int row = blockIdx.x * 4 + wave;
    int s = row_start[row];
    int e = row_start[row + 1];

    float ax = 0.0f, ay = 0.0f;
    for (int base = s; base < e; base += 64) {
        int j = base + lane;
        int cl = 0;
        float vl = 0.0f;
        if (j < e) { cl = csr_col[j]; vl = csr_val[j]; }
        int cnt = e - base; if (cnt > 64) cnt = 64;
        int k = 0;
        for (; k + 4 <= cnt; k += 4) {
            int c0 = __shfl(cl, k);
            int c1 = __shfl(cl, k + 1);
            int c2 = __shfl(cl, k + 2);
            int c3 = __shfl(cl, k + 3);
            float v0 = __shfl(vl, k);
            float v1 = __shfl(vl, k + 1);
            float v2 = __shfl(vl, k + 2);
            float v3 = __shfl(vl, k + 3);
            unsigned int p0 = x[(size_t)c0 * 64 + lane];
            unsigned int p1 = x[(size_t)c1 * 64 + lane];
            unsigned int p2 = x[(size_t)c2 * 64 + lane];
            unsigned int p3 = x[(size_t)c3 * 64 + lane];
            ax += v0 * blo(p0); ay += v0 * bhi(p0);
            ax += v1 * blo(p1); ay += v1 * bhi(p1);
            ax += v2 * blo(p2); ay += v2 * bhi(p2);
            ax += v3 * blo(p3); ay += v3 * bhi(p3);
        }
        for (; k < cnt; ++k) {
            int c = __shfl(cl, k);
            float v = __shfl(vl, k);
            unsigned int p = x[(size_t)c * 64 + lane];
            ax += v * blo(p);
            ay += v * bhi(p);
        }
    }
    float id = 1.0f / deg[row];
    ax *= id;
    ay *= id;

    x_next[(size_t)row * 64 + lane] = pack2bf(ax, ay);

    float ss = ax * ax + ay * ay;
#pragma unroll
    for (int off = 32; off > 0; off >>= 1) ss += __shfl_down(ss, off);
    ss = __shfl(ss, 0);
    float nrm = fmaxf(sqrtf(ss), 1e-12f);
    float w = weight / nrm;

    float2* acc2 = (float2*)acc;
    size_t idx = (size_t)row * 64 + lane;
    if (overwrite) {
        float2 p; p.x = ax * w; p.y = ay * w;
        acc2[idx] = p;
    } else {
        float2 p = acc2[idx];
        p.x += ax * w;
        p.y += ay * w;
        acc2[idx] = p;
    }
}

// ---------------- column statistics (double accumulation) ----------------
static __global__ void colstats_kernel(const float* __restrict__ acc,
                                       double* __restrict__ csum, double* __restrict__ csumsq, int n) {
    int col = threadIdx.x;  // 0..127
    double s = 0.0, q = 0.0;
    for (int r = blockIdx.x; r < n; r += gridDim.x) {
        float v = acc[r * DD + col];
        s += (double)v;
        q += (double)v * (double)v;
    }
    atomicAdd(&csum[col], s);
    atomicAdd(&csumsq[col], q);
}

static __global__ void stats_kernel(const double* __restrict__ csum, const double* __restrict__ csumsq,
                                    float* __restrict__ mean, float* __restrict__ invstd, int n) {
    int c = threadIdx.x;  // 128 threads
    double m = csum[c] / (double)n;
    double var = (csumsq[c] - (double)n * m * m) / (double)(n - 1);
    if (var < 0.0) var = 0.0;
    double sd = sqrt(var);
    if (sd == 0.0) sd = 1.0;
    mean[c] = (float)m;
    invstd[c] = (float)(1.0 / sd);
}

static __global__ void normalize_kernel(float* __restrict__ out, const float* __restrict__ mean,
                                        const float* __restrict__ invstd, int total) {
    int i = blockIdx.x * blockDim.x + threadIdx.x;
    if (i < total) {
        int c = i & 127;
        out[i] = (out[i] - mean[c]) * invstd[c];
    }
}

extern "C" void kernel_launch(void* const* d_in, const int* in_sizes, int n_in,
                              void* d_out, int out_size, void* d_ws, size_t ws_size,
                              hipStream_t stream) {
    const int* erow = (const int*)d_in[0];
    const int* ecol = (const int*)d_in[1];
    const float* eval_ = (const float*)d_in[2];
    const float* R = (const float*)d_in[3];
    float* out = (float*)d_out;  // acc lives here, normalized in place at the end

    // workspace layout
    char* ws = (char*)d_ws;
    size_t off = 0;
    auto alloc = [&](size_t bytes) -> char* {
        char* p = ws + off;
        off += (bytes + 255) & ~(size_t)255;
        return p;
    };
    float* deg        = (float*)alloc(NN * sizeof(float));
    int* counts       = (int*)alloc(NN * sizeof(int));
    int* counts_rep   = (int*)alloc((size_t)NREP * NN * sizeof(int));
    int* rep_base     = (int*)alloc((size_t)NREP * NN * sizeof(int));
    int* cursor_rep   = (int*)alloc((size_t)NREP * NN * sizeof(int));
    int* row_start    = (int*)alloc((NN + 1) * sizeof(int));
    int* partials     = (int*)alloc(SCAN_NBLK * sizeof(int));
    int* csr_col      = (int*)alloc(NE * sizeof(int));
    float* csr_val    = (float*)alloc(NE * sizeof(float));
    unsigned int* x_a = (unsigned int*)alloc((size_t)NN * 64 * sizeof(unsigned int));  // bf16 packed
    unsigned int* x_b = (unsigned int*)alloc((size_t)NN * 64 * sizeof(unsigned int));
    double* csum      = (double*)alloc(DD * sizeof(double));
    double* csumsq    = (double*)alloc(DD * sizeof(double));
    float* meanbuf    = (float*)alloc(DD * sizeof(float));
    float* invstdb    = (float*)alloc(DD * sizeof(float));

    // zero what we accumulate into (ws is poisoned 0xAA before every call)
    hipMemsetAsync(counts_rep, 0, (size_t)NREP * NN * sizeof(int), stream);
    hipMemsetAsync(cursor_rep, 0, (size_t)NREP * NN * sizeof(int), stream);
    hipMemsetAsync(csum, 0, DD * sizeof(double), stream);
    hipMemsetAsync(csumsq, 0, DD * sizeof(double), stream);

    const int total = NN * DD;
    const int npairs = total / 2;

    count_kernel<<<(NE + 255) / 256, 256, 0, stream>>>(erow, counts_rep, NE);
    rep_prefix_kernel<<<(NN + 255) / 256, 256, 0, stream>>>(counts_rep, rep_base, counts, NN);

    scan_phase1<<<SCAN_NBLK, SCAN_BS, 0, stream>>>(counts, partials, NN);
    scan_phase2<<<1, SCAN_BS, 0, stream>>>(partials, row_start, SCAN_NBLK);
    scan_phase3<<<SCAN_NBLK, SCAN_BS, 0, stream>>>(counts, partials, row_start, NN);

    scatter_kernel<<<(NE + 255) / 256, 256, 0, stream>>>(erow, ecol, eval_, row_start, rep_base,
                                                         cursor_rep, csr_col, csr_val, NE);

    deg_from_csr_kernel<<<(NN + 255) / 256, 256, 0, stream>>>(row_start, csr_val, deg, NN);
    init_x_kernel<<<(npairs + 255) / 256, 256, 0, stream>>>(R, deg, x_a, npairs);

    const float weights[4] = {1.0f, 1.0f, 7.81f, 45.28f};
    unsigned int* xs[2] = {x_a, x_b};
    for (int i = 0; i < 4; ++i) {
        spmm_fused_kernel<<<NN / 4, 256, 0, stream>>>(row_start, csr_col, csr_val,
                                                      xs[i & 1], deg, xs[(i + 1) & 1],
                                                      out, weights[i], i == 0 ? 1 : 0);
    }

    colstats_kernel<<<512, DD, 0, stream>>>(out, csum, csumsq, NN);
    stats_kernel<<<1, DD, 0, stream>>>(csum, csumsq, meanbuf, invstdb, NN);
    normalize_kernel<<<(total + 255) / 256, 256, 0, stream>>>(out, meanbuf, invstdb, total);
}

// Round 5
// 329.250 us; speedup vs baseline: 1.9227x; 1.2208x over previous
//
#include <hip/hip_runtime.h>
#include <math.h>

#define NN 50000
#define NE 800000
#define DD 128
#define NBKT 196            // coarse buckets: row >> 8
#define BCAP 5120           // per-bucket capacity (mean 4082, sigma ~64 -> 16 sigma margin)
#define CHUNK 2048          // edges per bin_kernel block
#define NCHUNK ((NE + CHUNK - 1) / CHUNK)   // 391

// ---------------- bf16 helpers (x stored as bf16 pairs packed in uint) ----------------
static __device__ __forceinline__ float blo(unsigned int p) { return __uint_as_float(p << 16); }
static __device__ __forceinline__ float bhi(unsigned int p) { return __uint_as_float(p & 0xffff0000u); }
static __device__ __forceinline__ unsigned int pack2bf(float a, float b) {
    unsigned int ua = __float_as_uint(a);
    unsigned int ub = __float_as_uint(b);
    ua = ua + 0x7FFFu + ((ua >> 16) & 1u);
    ub = ub + 0x7FFFu + ((ub >> 16) & 1u);
    return (ua >> 16) | (ub & 0xffff0000u);
}

// ---------------- pass 1: LDS counting-sort edges into 196 coarse buckets ----------------
// payload: uint2{ row | col<<16, val_bits }  (row, col < 65536)
static __global__ __launch_bounds__(256) void bin_kernel(
    const int* __restrict__ erow, const int* __restrict__ ecol, const float* __restrict__ eval_,
    int* __restrict__ bucket_cursor, uint2* __restrict__ binned) {
    __shared__ uint2 sorted[CHUNK];
    __shared__ unsigned short sbin[CHUNK];
    __shared__ int hist[NBKT];
    __shared__ int bstart[NBKT];
    __shared__ int bcur[NBKT];
    __shared__ int gbase[NBKT];
    __shared__ int tmp[256];

    int t = threadIdx.x;
    int cbase = blockIdx.x * CHUNK;
    int cn = NE - cbase; if (cn > CHUNK) cn = CHUNK;

    for (int i = t; i < NBKT; i += 256) hist[i] = 0;
    __syncthreads();

    unsigned int rc[8]; unsigned int vv[8]; int bb[8];
    int nloc = 0;
    for (int i = t; i < cn; i += 256) {
        int g = cbase + i;
        int r = erow[g];
        int c = ecol[g];
        float v = eval_[g];
        rc[nloc] = (unsigned)r | ((unsigned)c << 16);
        vv[nloc] = __float_as_uint(v);
        int b = r >> 8;
        bb[nloc] = b;
        atomicAdd(&hist[b], 1);
        ++nloc;
    }
    __syncthreads();

    // exclusive scan of hist -> bstart (256-thread Hillis-Steele)
    int hv = (t < NBKT) ? hist[t] : 0;
    tmp[t] = hv;
    __syncthreads();
    for (int off = 1; off < 256; off <<= 1) {
        int u = (t >= off) ? tmp[t - off] : 0;
        __syncthreads();
        tmp[t] += u;
        __syncthreads();
    }
    if (t < NBKT) {
        int ex = tmp[t] - hv;
        bstart[t] = ex;
        bcur[t] = ex;
        gbase[t] = atomicAdd(&bucket_cursor[t], hv);  // reserve contiguous run in bucket region
    }
    __syncthreads();

    // scatter into LDS (sorted by bucket)
    for (int k = 0; k < nloc; ++k) {
        int pos = atomicAdd(&bcur[bb[k]], 1);
        sorted[pos] = make_uint2(rc[k], vv[k]);
        sbin[pos] = (unsigned short)bb[k];
    }
    __syncthreads();

    // coalesced write-out: consecutive i in same bucket -> consecutive global slots
    for (int i = t; i < cn; i += 256) {
        int b = sbin[i];
        binned[(size_t)b * BCAP + gbase[b] + (i - bstart[b])] = sorted[i];
    }
}

// ---------------- exclusive scan of bucket totals ----------------
static __global__ void bucket_scan_kernel(const int* __restrict__ bucket_cursor,
                                          int* __restrict__ bucket_base) {
    __shared__ int tmp[256];
    int t = threadIdx.x;
    int v = (t < NBKT) ? bucket_cursor[t] : 0;
    tmp[t] = v;
    __syncthreads();
    for (int off = 1; off < 256; off <<= 1) {
        int u = (t >= off) ? tmp[t - off] : 0;
        __syncthreads();
        tmp[t] += u;
        __syncthreads();
    }
    if (t < NBKT) bucket_base[t] = tmp[t] - v;
}

// ---------------- pass 2: per-bucket sort by row -> final CSR + row_start ----------------
static __global__ __launch_bounds__(256) void sort_kernel(
    const uint2* __restrict__ binned, const int* __restrict__ bucket_cursor,
    const int* __restrict__ bucket_base, uint2* __restrict__ csr, int* __restrict__ row_start) {
    __shared__ uint2 buf[BCAP];
    __shared__ int hist[256];
    __shared__ int rcur[256];
    int b = blockIdx.x;
    int t = threadIdx.x;
    int cnt = bucket_cursor[b];
    int gb = bucket_base[b];
    int lo = b << 8;

    hist[t] = 0;
    __syncthreads();
    for (int i = t; i < cnt; i += 256) {
        uint2 e = binned[(size_t)b * BCAP + i];
        buf[i] = e;
        atomicAdd(&hist[(e.x & 0xFFFFu) - lo], 1);
    }
    __syncthreads();
    int hv = hist[t];
    rcur[t] = hv;  // use as inclusive-scan temp
    __syncthreads();
    for (int off = 1; off < 256; off <<= 1) {
        int u = (t >= off) ? rcur[t - off] : 0;
        __syncthreads();
        rcur[t] += u;
        __syncthreads();
    }
    int excl = rcur[t] - hv;
    int r = lo + t;
    if (r < NN) row_start[r] = gb + excl;
    if (b == NBKT - 1 && t == 255) row_start[NN] = gb + cnt;
    rcur[t] = excl;
    __syncthreads();
    // scatter to final CSR (block-private contiguous region -> single-XCD L2-local)
    for (int i = t; i < cnt; i += 256) {
        uint2 e = buf[i];
        int rr = (int)(e.x & 0xFFFFu) - lo;
        int pos = atomicAdd(&rcur[rr], 1);
        csr[(size_t)gb + pos] = make_uint2(e.x >> 16, e.y);
    }
}

// ---------------- degree from CSR row sums (no atomics), clamp zeros ----------------
static __global__ void deg_from_csr_kernel(const int* __restrict__ row_start,
                                           const uint2* __restrict__ csr,
                                           float* __restrict__ deg, int n) {
    int r = blockIdx.x * blockDim.x + threadIdx.x;
    if (r < n) {
        int s = row_start[r], e = row_start[r + 1];
        float sum = 0.0f;
        for (int j = s; j < e; ++j) sum += __uint_as_float(csr[j].y);
        deg[r] = (sum == 0.0f) ? 1.0f : sum;
    }
}

// x0 = R * deg^(-0.5), stored bf16-packed (one uint = 2 cols)
static __global__ void init_x_kernel(const float* __restrict__ R, const float* __restrict__ deg,
                                     unsigned int* __restrict__ xq, int npairs) {
    int i = blockIdx.x * blockDim.x + threadIdx.x;
    if (i < npairs) {
        float d = deg[i >> 6];  // 64 uints per row
        float sc = rsqrtf(d);
        float a = R[2 * i] * sc;
        float b = R[2 * i + 1] * sc;
        xq[i] = pack2bf(a, b);
    }
}

// ---------------- fused SpMM + inv_deg + row-normalize + weighted accumulate ----------------
// 256 threads = 4 waves per block; one wave per row; lane owns 2 columns (bf16 pair)
static __global__ __launch_bounds__(256) void spmm_fused_kernel(
    const int* __restrict__ row_start, const uint2* __restrict__ csr,
    const unsigned int* __restrict__ x, const float* __restrict__ deg,
    unsigned int* __restrict__ x_next, float* __restrict__ acc, float weight, int overwrite) {
    int wave = threadIdx.x >> 6;
    int lane = threadIdx.x & 63;
    int row = blockIdx.x * 4 + wave;
    int s = row_start[row];
    int e = row_start[row + 1];

    float ax = 0.0f, ay = 0.0f;
    for (int base = s; base < e; base += 64) {
        int j = base + lane;
        int cl = 0;
        float vl = 0.0f;
        if (j < e) { uint2 t2 = csr[j]; cl = (int)t2.x; vl = __uint_as_float(t2.y); }
        int cnt = e - base; if (cnt > 64) cnt = 64;
        int k = 0;
        for (; k + 4 <= cnt; k += 4) {
            int c0 = __shfl(cl, k);
            int c1 = __shfl(cl, k + 1);
            int c2 = __shfl(cl, k + 2);
            int c3 = __shfl(cl, k + 3);
            float v0 = __shfl(vl, k);
            float v1 = __shfl(vl, k + 1);
            float v2 = __shfl(vl, k + 2);
            float v3 = __shfl(vl, k + 3);
            unsigned int p0 = x[(size_t)c0 * 64 + lane];
            unsigned int p1 = x[(size_t)c1 * 64 + lane];
            unsigned int p2 = x[(size_t)c2 * 64 + lane];
            unsigned int p3 = x[(size_t)c3 * 64 + lane];
            ax += v0 * blo(p0); ay += v0 * bhi(p0);
            ax += v1 * blo(p1); ay += v1 * bhi(p1);
            ax += v2 * blo(p2); ay += v2 * bhi(p2);
            ax += v3 * blo(p3); ay += v3 * bhi(p3);
        }
        for (; k < cnt; ++k) {
            int c = __shfl(cl, k);
            float v = __shfl(vl, k);
            unsigned int p = x[(size_t)c * 64 + lane];
            ax += v * blo(p);
            ay += v * bhi(p);
        }
    }
    float id = 1.0f / deg[row];
    ax *= id;
    ay *= id;

    x_next[(size_t)row * 64 + lane] = pack2bf(ax, ay);

    float ss = ax * ax + ay * ay;
#pragma unroll
    for (int off = 32; off > 0; off >>= 1) ss += __shfl_down(ss, off);
    ss = __shfl(ss, 0);
    float nrm = fmaxf(sqrtf(ss), 1e-12f);
    float w = weight / nrm;

    float2* acc2 = (float2*)acc;
    size_t idx = (size_t)row * 64 + lane;
    if (overwrite) {
        float2 p; p.x = ax * w; p.y = ay * w;
        acc2[idx] = p;
    } else {
        float2 p = acc2[idx];
        p.x += ax * w;
        p.y += ay * w;
        acc2[idx] = p;
    }
}

// ---------------- column statistics (double accumulation) ----------------
static __global__ void colstats_kernel(const float* __restrict__ acc,
                                       double* __restrict__ csum, double* __restrict__ csumsq, int n) {
    int col = threadIdx.x;  // 0..127
    double s = 0.0, q = 0.0;
    for (int r = blockIdx.x; r < n; r += gridDim.x) {
        float v = acc[r * DD + col];
        s += (double)v;
        q += (double)v * (double)v;
    }
    atomicAdd(&csum[col], s);
    atomicAdd(&csumsq[col], q);
}

static __global__ void stats_kernel(const double* __restrict__ csum, const double* __restrict__ csumsq,
                                    float* __restrict__ mean, float* __restrict__ invstd, int n) {
    int c = threadIdx.x;  // 128 threads
    double m = csum[c] / (double)n;
    double var = (csumsq[c] - (double)n * m * m) / (double)(n - 1);
    if (var < 0.0) var = 0.0;
    double sd = sqrt(var);
    if (sd == 0.0) sd = 1.0;
    mean[c] = (float)m;
    invstd[c] = (float)(1.0 / sd);
}

static __global__ void normalize_kernel(float* __restrict__ out, const float* __restrict__ mean,
                                        const float* __restrict__ invstd, int total) {
    int i = blockIdx.x * blockDim.x + threadIdx.x;
    if (i < total) {
        int c = i & 127;
        out[i] = (out[i] - mean[c]) * invstd[c];
    }
}

extern "C" void kernel_launch(void* const* d_in, const int* in_sizes, int n_in,
                              void* d_out, int out_size, void* d_ws, size_t ws_size,
                              hipStream_t stream) {
    const int* erow = (const int*)d_in[0];
    const int* ecol = (const int*)d_in[1];
    const float* eval_ = (const float*)d_in[2];
    const float* R = (const float*)d_in[3];
    float* out = (float*)d_out;  // acc lives here, normalized in place at the end

    // workspace layout
    char* ws = (char*)d_ws;
    size_t off = 0;
    auto alloc = [&](size_t bytes) -> char* {
        char* p = ws + off;
        off += (bytes + 255) & ~(size_t)255;
        return p;
    };
    float* deg          = (float*)alloc(NN * sizeof(float));
    int* bucket_cursor  = (int*)alloc(NBKT * sizeof(int));
    int* bucket_base    = (int*)alloc(NBKT * sizeof(int));
    int* row_start      = (int*)alloc((NN + 1) * sizeof(int));
    uint2* binned       = (uint2*)alloc((size_t)NBKT * BCAP * sizeof(uint2));
    uint2* csr          = (uint2*)alloc((size_t)NE * sizeof(uint2));
    unsigned int* x_a   = (unsigned int*)alloc((size_t)NN * 64 * sizeof(unsigned int));  // bf16 packed
    unsigned int* x_b   = (unsigned int*)alloc((size_t)NN * 64 * sizeof(unsigned int));
    double* csum        = (double*)alloc(DD * sizeof(double));
    double* csumsq      = (double*)alloc(DD * sizeof(double));
    float* meanbuf      = (float*)alloc(DD * sizeof(float));
    float* invstdb      = (float*)alloc(DD * sizeof(float));

    // zero what we accumulate into (ws is poisoned 0xAA before every call)
    hipMemsetAsync(bucket_cursor, 0, NBKT * sizeof(int), stream);
    hipMemsetAsync(csum, 0, DD * sizeof(double), stream);
    hipMemsetAsync(csumsq, 0, DD * sizeof(double), stream);

    const int total = NN * DD;
    const int npairs = total / 2;

    bin_kernel<<<NCHUNK, 256, 0, stream>>>(erow, ecol, eval_, bucket_cursor, binned);
    bucket_scan_kernel<<<1, 256, 0, stream>>>(bucket_cursor, bucket_base);
    sort_kernel<<<NBKT, 256, 0, stream>>>(binned, bucket_cursor, bucket_base, csr, row_start);

    deg_from_csr_kernel<<<(NN + 255) / 256, 256, 0, stream>>>(row_start, csr, deg, NN);
    init_x_kernel<<<(npairs + 255) / 256, 256, 0, stream>>>(R, deg, x_a, npairs);

    const float weights[4] = {1.0f, 1.0f, 7.81f, 45.28f};
    unsigned int* xs[2] = {x_a, x_b};
    for (int i = 0; i < 4; ++i) {
        spmm_fused_kernel<<<NN / 4, 256, 0, stream>>>(row_start, csr,
                                                      xs[i & 1], deg, xs[(i + 1) & 1],
                                                      out, weights[i], i == 0 ? 1 : 0);
    }

    colstats_kernel<<<512, DD, 0, stream>>>(out, csum, csumsq, NN);
    stats_kernel<<<1, DD, 0, stream>>>(csum, csumsq, meanbuf, invstdb, NN);
    normalize_kernel<<<(total + 255) / 256, 256, 0, stream>>>(out, meanbuf, invstdb, total);
}